// Round 4
// baseline (476.601 us; speedup 1.0000x reference)
//
#include <hip/hip_runtime.h>

// Stream compaction:
//   mask[i]  = accept_index[i] >= 0
//   dst[i]   = exclusive_prefix_sum(mask)[i]
//   out[dst[i]] = out_cache_loc[accept_index[i]]  for mask[i]
//   out[total..N) = 0
//
// R3 counters: FETCH 750MB = full 64B line per random gather (zero reuse),
// 3.1 TB/s = HBM random-row (tRC) ceiling. R4: slice-swept gather — keep the
// 16 indices + LDS positions in registers, sweep the 64MB table in 16 x 4MB
// slices so the hot window is L3/L2-resident and each table line is fetched
// ~once instead of ~11.7x. Gathers are plain loads (want cache retention);
// output stores stay nontemporal (streamed once).

#define N_TOTAL  16777216
#define BLOCK    256
#define EPT      16                   // elements per thread
#define TILE     (BLOCK * EPT)        // 4096
#define NBLOCKS  (N_TOTAL / TILE)     // 4096
#define SLICE_LG 20                   // 2^20 elements = 4 MB per slice
#define SLICES   (N_TOTAL >> SLICE_LG) // 16

typedef float vfloat4 __attribute__((ext_vector_type(4)));

// ---------------- pass 1: per-block count of accepted ----------------
__global__ __launch_bounds__(BLOCK) void k_reduce(const int* __restrict__ idx,
                                                  int* __restrict__ blockSums) {
    const int b = blockIdx.x;
    const int t = threadIdx.x;
    const int4* p = (const int4*)(idx + (size_t)b * TILE + (size_t)t * EPT);
    int cnt = 0;
#pragma unroll
    for (int j = 0; j < EPT / 4; ++j) {
        int4 v = p[j];
        cnt += (v.x >= 0) + (v.y >= 0) + (v.z >= 0) + (v.w >= 0);
    }
#pragma unroll
    for (int d = 32; d > 0; d >>= 1) cnt += __shfl_down(cnt, d);
    __shared__ int wsum[BLOCK / 64];
    const int lane = t & 63, wave = t >> 6;
    if (lane == 0) wsum[wave] = cnt;
    __syncthreads();
    if (t == 0) {
        int s = 0;
#pragma unroll
        for (int w = 0; w < BLOCK / 64; ++w) s += wsum[w];
        blockSums[b] = s;
    }
}

// ---------------- pass 2: exclusive scan of 4096 block sums (1 block) ----------------
__global__ __launch_bounds__(256) void k_scan(const int* __restrict__ blockSums,
                                              int* __restrict__ blockOffsets) {
    const int t = threadIdx.x;          // 256 threads x 16 values = 4096
    const int lane = t & 63, wave = t >> 6;
    int vals[16];
    const int4* p = (const int4*)(blockSums + t * 16);
#pragma unroll
    for (int j = 0; j < 4; ++j) {
        int4 v = p[j];
        vals[4 * j + 0] = v.x; vals[4 * j + 1] = v.y;
        vals[4 * j + 2] = v.z; vals[4 * j + 3] = v.w;
    }
    int tsum = 0;
#pragma unroll
    for (int j = 0; j < 16; ++j) tsum += vals[j];

    int x = tsum;
#pragma unroll
    for (int d = 1; d < 64; d <<= 1) {
        int y = __shfl_up(x, d);
        if (lane >= d) x += y;
    }
    __shared__ int wsum[4], woff[4];
    if (lane == 63) wsum[wave] = x;
    __syncthreads();
    if (t == 0) {
        int s = 0;
#pragma unroll
        for (int w = 0; w < 4; ++w) { woff[w] = s; s += wsum[w]; }
        blockOffsets[NBLOCKS] = s;   // grand total for tail-zero pass
    }
    __syncthreads();
    int run = (x - tsum) + woff[wave];
#pragma unroll
    for (int j = 0; j < 16; ++j) {
        blockOffsets[t * 16 + j] = run;
        run += vals[j];
    }
}

// ---------------- pass 3: slice-swept gather + LDS-compact + coalesced store ----------------
__global__ __launch_bounds__(BLOCK) void k_scatter(const int* __restrict__ idx,
                                                   const float* __restrict__ src,
                                                   const int* __restrict__ blockOffsets,
                                                   float* __restrict__ out) {
    const int b = blockIdx.x;
    const int t = threadIdx.x;
    const int lane = t & 63, wave = t >> 6;
    const int4* p = (const int4*)(idx + (size_t)b * TILE + (size_t)t * EPT);
    int v[EPT];
#pragma unroll
    for (int j = 0; j < EPT / 4; ++j) {
        int4 q = p[j];
        v[4 * j + 0] = q.x; v[4 * j + 1] = q.y;
        v[4 * j + 2] = q.z; v[4 * j + 3] = q.w;
    }

    int cnt = 0;
#pragma unroll
    for (int j = 0; j < EPT; ++j) cnt += (v[j] >= 0);

    // block exclusive scan of per-thread counts
    int x = cnt;
#pragma unroll
    for (int d = 1; d < 64; d <<= 1) {
        int y = __shfl_up(x, d);
        if (lane >= d) x += y;
    }
    __shared__ int wsum[BLOCK / 64], woff[BLOCK / 64];
    __shared__ int btotal;
    if (lane == 63) wsum[wave] = x;
    __syncthreads();
    if (t == 0) {
        int s = 0;
#pragma unroll
        for (int w = 0; w < BLOCK / 64; ++w) { woff[w] = s; s += wsum[w]; }
        btotal = s;
    }
    __syncthreads();

    // precompute each element's LDS destination (original-order compaction)
    int pos[EPT];
    {
        int off = (x - cnt) + woff[wave];
#pragma unroll
        for (int j = 0; j < EPT; ++j)
            if (v[j] >= 0) pos[j] = off++;
    }

    // slice-swept gather: all blocks sweep the table in the same slice order,
    // so the hot table window is ~1-2 slices (4-8 MB) -> L2/L3-resident.
    // Rejected lanes (v=-1 -> 0xFFF after unsigned shift) match no slice.
    __shared__ float vals[TILE];
#pragma unroll 1
    for (int s = 0; s < SLICES; ++s) {
#pragma unroll
        for (int j = 0; j < EPT; ++j) {
            if ((int)((unsigned)v[j] >> SLICE_LG) == s)
                vals[pos[j]] = src[v[j]];
        }
    }
    __syncthreads();

    // contiguous, fully-coalesced block write: [base, base+btotal)
    const int base = blockOffsets[b];
    const int tot  = btotal;
    for (int i = t; i < tot; i += BLOCK)
        __builtin_nontemporal_store(vals[i], out + base + i);
}

// ---------------- pass 4: zero the tail [total, N) ----------------
__global__ __launch_bounds__(256) void k_tail(float* __restrict__ out,
                                              const int* __restrict__ total_p) {
    const int total = *total_p;
    const int i = (blockIdx.x * 256 + threadIdx.x) * 4;
    if (i >= total) {
        vfloat4 z = (vfloat4)(0.f);
        __builtin_nontemporal_store(z, (vfloat4*)(out + i));
    } else if (i + 4 > total) {
#pragma unroll
        for (int k = 0; k < 4; ++k)
            if (i + k >= total) out[i + k] = 0.f;
    }
}

extern "C" void kernel_launch(void* const* d_in, const int* in_sizes, int n_in,
                              void* d_out, int out_size, void* d_ws, size_t ws_size,
                              hipStream_t stream) {
    const int*   idx = (const int*)d_in[0];     // accept_index (int32 per harness)
    const float* src = (const float*)d_in[1];   // out_cache_loc
    float*       out = (float*)d_out;

    int* blockSums    = (int*)d_ws;             // NBLOCKS ints
    int* blockOffsets = blockSums + NBLOCKS;    // NBLOCKS+1 ints (last = total)

    k_reduce <<<NBLOCKS, BLOCK, 0, stream>>>(idx, blockSums);
    k_scan   <<<1, 256, 0, stream>>>(blockSums, blockOffsets);
    k_scatter<<<NBLOCKS, BLOCK, 0, stream>>>(idx, src, blockOffsets, out);
    k_tail   <<<N_TOTAL / 4 / 256, 256, 0, stream>>>(out, blockOffsets + NBLOCKS);
}

// Round 5
// 342.713 us; speedup vs baseline: 1.3907x; 1.3907x over previous
//
#include <hip/hip_runtime.h>

// Stream compaction:
//   mask[i]  = accept_index[i] >= 0
//   dst[i]   = exclusive_prefix_sum(mask)[i]
//   out[dst[i]] = out_cache_loc[accept_index[i]]  for mask[i]
//   out[total..N) = 0
//
// R4 post-mortem: 16-slice sweep captured reuse (FETCH 750->537MB) but the
// per-element load->ds_write dependency forced vmcnt(0) per element -> MLP ~1
// -> 1.76 TB/s. R5: 4 x 16MB slices, branch-free batched gather per slice
// (32 unconditional loads, non-matching lanes read the hot src[0] line, ONE
// explicit vmcnt(0), then conditional LDS commit) -> ~8-deep MLP preserved
// while keeping slice temporal locality for L2/L3 reuse.

#define N_TOTAL  16777216
#define BLOCK    256

// reduce/scan tiling (unchanged from R1)
#define EPT      16
#define TILE     (BLOCK * EPT)        // 4096
#define NBLOCKS  (N_TOTAL / TILE)     // 4096

// scatter tiling
#define EPT2     32
#define TILE2    (BLOCK * EPT2)       // 8192
#define NB2      (N_TOTAL / TILE2)    // 2048

#define SLICE_LG 22                   // 2^22 elements = 16 MB per slice
#define SLICES   (N_TOTAL >> SLICE_LG) // 4

typedef float vfloat4 __attribute__((ext_vector_type(4)));

// ---------------- pass 1: per-tile count of accepted ----------------
__global__ __launch_bounds__(BLOCK) void k_reduce(const int* __restrict__ idx,
                                                  int* __restrict__ blockSums) {
    const int b = blockIdx.x;
    const int t = threadIdx.x;
    const int4* p = (const int4*)(idx + (size_t)b * TILE + (size_t)t * EPT);
    int cnt = 0;
#pragma unroll
    for (int j = 0; j < EPT / 4; ++j) {
        int4 v = p[j];
        cnt += (v.x >= 0) + (v.y >= 0) + (v.z >= 0) + (v.w >= 0);
    }
#pragma unroll
    for (int d = 32; d > 0; d >>= 1) cnt += __shfl_down(cnt, d);
    __shared__ int wsum[BLOCK / 64];
    const int lane = t & 63, wave = t >> 6;
    if (lane == 0) wsum[wave] = cnt;
    __syncthreads();
    if (t == 0) {
        int s = 0;
#pragma unroll
        for (int w = 0; w < BLOCK / 64; ++w) s += wsum[w];
        blockSums[b] = s;
    }
}

// ---------------- pass 2: exclusive scan of 4096 tile sums (1 block) ----------------
__global__ __launch_bounds__(256) void k_scan(const int* __restrict__ blockSums,
                                              int* __restrict__ blockOffsets) {
    const int t = threadIdx.x;          // 256 threads x 16 values = 4096
    const int lane = t & 63, wave = t >> 6;
    int vals[16];
    const int4* p = (const int4*)(blockSums + t * 16);
#pragma unroll
    for (int j = 0; j < 4; ++j) {
        int4 v = p[j];
        vals[4 * j + 0] = v.x; vals[4 * j + 1] = v.y;
        vals[4 * j + 2] = v.z; vals[4 * j + 3] = v.w;
    }
    int tsum = 0;
#pragma unroll
    for (int j = 0; j < 16; ++j) tsum += vals[j];

    int x = tsum;
#pragma unroll
    for (int d = 1; d < 64; d <<= 1) {
        int y = __shfl_up(x, d);
        if (lane >= d) x += y;
    }
    __shared__ int wsum[4], woff[4];
    if (lane == 63) wsum[wave] = x;
    __syncthreads();
    if (t == 0) {
        int s = 0;
#pragma unroll
        for (int w = 0; w < 4; ++w) { woff[w] = s; s += wsum[w]; }
        blockOffsets[NBLOCKS] = s;   // grand total for tail-zero pass
    }
    __syncthreads();
    int run = (x - tsum) + woff[wave];
#pragma unroll
    for (int j = 0; j < 16; ++j) {
        blockOffsets[t * 16 + j] = run;
        run += vals[j];
    }
}

// ---------------- pass 3: slice-swept batched gather + LDS-compact + coalesced store ----------------
__global__ __launch_bounds__(BLOCK) void k_scatter(const int* __restrict__ idx,
                                                   const float* __restrict__ src,
                                                   const int* __restrict__ blockOffsets,
                                                   float* __restrict__ out) {
    const int b = blockIdx.x;
    const int t = threadIdx.x;
    const int lane = t & 63, wave = t >> 6;
    const int4* p = (const int4*)(idx + (size_t)b * TILE2 + (size_t)t * EPT2);
    int v[EPT2];
#pragma unroll
    for (int j = 0; j < EPT2 / 4; ++j) {
        int4 q = p[j];
        v[4 * j + 0] = q.x; v[4 * j + 1] = q.y;
        v[4 * j + 2] = q.z; v[4 * j + 3] = q.w;
    }

    int cnt = 0;
#pragma unroll
    for (int j = 0; j < EPT2; ++j) cnt += (v[j] >= 0);

    // block exclusive scan of per-thread counts
    int x = cnt;
#pragma unroll
    for (int d = 1; d < 64; d <<= 1) {
        int y = __shfl_up(x, d);
        if (lane >= d) x += y;
    }
    __shared__ int wsum[BLOCK / 64], woff[BLOCK / 64];
    __shared__ int btotal;
    if (lane == 63) wsum[wave] = x;
    __syncthreads();
    if (t == 0) {
        int s = 0;
#pragma unroll
        for (int w = 0; w < BLOCK / 64; ++w) { woff[w] = s; s += wsum[w]; }
        btotal = s;
    }
    __syncthreads();
    const int off0 = (x - cnt) + woff[wave];   // this thread's first LDS slot

    // slice-swept gather: all blocks sweep the 64MB table in 4 x 16MB slices.
    // Per slice: 32 BRANCH-FREE loads (non-matching lanes read src[0], which
    // stays L1/L2-hot) -> one vmcnt(0) -> conditional LDS commit. This keeps
    // ~8 real loads in flight per thread per slice (vs R4's serialized 1).
    __shared__ float vals[TILE2];
#pragma unroll 1
    for (int s = 0; s < SLICES; ++s) {
        float tmp[EPT2];
#pragma unroll
        for (int j = 0; j < EPT2; ++j) {
            const bool m = (int)((unsigned)v[j] >> SLICE_LG) == s;
            tmp[j] = src[m ? v[j] : 0];
        }
        asm volatile("s_waitcnt vmcnt(0)" ::: "memory");
        int o = off0;
#pragma unroll
        for (int j = 0; j < EPT2; ++j) {
            const bool acc = v[j] >= 0;
            const bool m = (int)((unsigned)v[j] >> SLICE_LG) == s;
            if (m) vals[o] = tmp[j];
            o += acc;
        }
    }
    __syncthreads();

    // contiguous, fully-coalesced block write: [base, base+btotal)
    const int base = blockOffsets[2 * b];   // scatter tile = two reduce tiles
    const int tot  = btotal;
    for (int i = t; i < tot; i += BLOCK)
        __builtin_nontemporal_store(vals[i], out + base + i);
}

// ---------------- pass 4: zero the tail [total, N) ----------------
__global__ __launch_bounds__(256) void k_tail(float* __restrict__ out,
                                              const int* __restrict__ total_p) {
    const int total = *total_p;
    const int i = (blockIdx.x * 256 + threadIdx.x) * 4;
    if (i >= total) {
        vfloat4 z = (vfloat4)(0.f);
        __builtin_nontemporal_store(z, (vfloat4*)(out + i));
    } else if (i + 4 > total) {
#pragma unroll
        for (int k = 0; k < 4; ++k)
            if (i + k >= total) out[i + k] = 0.f;
    }
}

extern "C" void kernel_launch(void* const* d_in, const int* in_sizes, int n_in,
                              void* d_out, int out_size, void* d_ws, size_t ws_size,
                              hipStream_t stream) {
    const int*   idx = (const int*)d_in[0];     // accept_index (int32 per harness)
    const float* src = (const float*)d_in[1];   // out_cache_loc
    float*       out = (float*)d_out;

    int* blockSums    = (int*)d_ws;             // NBLOCKS ints
    int* blockOffsets = blockSums + NBLOCKS;    // NBLOCKS+1 ints (last = total)

    k_reduce <<<NBLOCKS, BLOCK, 0, stream>>>(idx, blockSums);
    k_scan   <<<1, 256, 0, stream>>>(blockSums, blockOffsets);
    k_scatter<<<NB2, BLOCK, 0, stream>>>(idx, src, blockOffsets, out);
    k_tail   <<<N_TOTAL / 4 / 256, 256, 0, stream>>>(out, blockOffsets + NBLOCKS);
}